// Round 5
// baseline (3529.951 us; speedup 1.0000x reference)
//
#include <hip/hip_runtime.h>
#include <math.h>

typedef unsigned long long ull;
typedef unsigned int u32;
typedef unsigned short u16;
typedef _Float16 half2v __attribute__((ext_vector_type(2)));
typedef __bf16 bf16x8 __attribute__((ext_vector_type(8)));
typedef float f32x4 __attribute__((ext_vector_type(4)));

#define H 512
#define STEPS 1024
#define OUTN 11

__device__ __forceinline__ float sigm(float x) { return 1.f / (1.f + __expf(-x)); }
__device__ __forceinline__ ull ld_pair(const ull* p) {
  return __hip_atomic_load((ull*)p, __ATOMIC_RELAXED, __HIP_MEMORY_SCOPE_AGENT);
}
__device__ __forceinline__ void st_pair(ull* p, ull v) {
  __hip_atomic_store(p, v, __ATOMIC_RELAXED, __HIP_MEMORY_SCOPE_AGENT);
}
// plain store: write-through L1 -> lands in the producer's XCD L2 (dirty).
// If consumer shares that L2 (co-located roles), an sc0 load sees it in ~250cy.
__device__ __forceinline__ void st_local(ull* p, ull v) {
  asm volatile("global_store_dwordx2 %0, %1, off" :: "v"(p), "v"(v) : "memory");
}
// Hybrid poll: 6 fast sc0 polls on the local shadow line, then one agent-scope
// rescue on the proven mailbox. Correctness rests ONLY on the rescue (exactly
// the R1 transport); the fast path is a pure accelerator. No hang possible.
__device__ __forceinline__ ull poll2(const ull* fast, const ull* slow, unsigned want) {
  for (;;) {
#pragma unroll 1
    for (int s = 0; s < 6; ++s) {
      ull r;
      asm volatile("global_load_dwordx2 %0, %1, off sc0\n\ts_waitcnt vmcnt(0)"
                   : "=v"(r) : "v"(fast) : "memory");
      if ((unsigned)(r >> 32) == want) return r;
    }
    ull r = __hip_atomic_load((ull*)slow, __ATOMIC_RELAXED, __HIP_MEMORY_SCOPE_AGENT);
    if ((unsigned)(r >> 32) == want) return r;
  }
}

__device__ __forceinline__ float dot2acc(half2v a, half2v b, float c) {
#if __has_builtin(__builtin_amdgcn_fdot2)
  return __builtin_amdgcn_fdot2(a, b, c, false);
#else
  return c + (float)a.x * (float)b.x + (float)a.y * (float)b.y;
#endif
}
__device__ __forceinline__ u16 f16bits(float x) {
  return __builtin_bit_cast(u16, (_Float16)x);
}
__device__ __forceinline__ half2v bch2(u32 u) { return __builtin_bit_cast(half2v, u); }

// ---------- in-place fp32 -> {bf16 hi, bf16 lo} repack (same 4B/elem) ----------
__device__ __forceinline__ u32 split_bf16(float x) {
  u32 u = __float_as_uint(x);
  u32 rh = (u + 0x7FFFu + ((u >> 16) & 1u)) & 0xFFFF0000u;
  float hf = __uint_as_float(rh);
  float lo = x - hf;
  u32 ul = __float_as_uint(lo);
  u32 rl = (ul + 0x7FFFu + ((ul >> 16) & 1u)) & 0xFFFF0000u;
  return (rh >> 16) | rl;
}

__global__ void cvt_split(float* __restrict__ A, float* __restrict__ B, int nA, int n4) {
  int idx = blockIdx.x * 256 + threadIdx.x;
  if (idx >= n4) return;
  int base = idx * 4;
  float* p = (base < nA) ? (A + base) : (B + (base - nA));
  float4 v = *(float4*)p;
  u32 r0 = split_bf16(v.x), r1 = split_bf16(v.y), r2 = split_bf16(v.z), r3 = split_bf16(v.w);
  uint4 o = make_uint4(r0, r1, r2, r3);
  *(uint4*)p = o;
}

// ---------- MFMA hi/lo bf16 GEMM: xp[M,N] += A[M,K] * B[N,K]^T (split-K atomic) ----------
__global__ __launch_bounds__(256, 2)
void gemm_hilo(const u32* __restrict__ A2, const u32* __restrict__ B2,
               float* __restrict__ C, int M, int N, int K)
{
  __shared__ __align__(16) u16 Ah[64 * 32], Al[64 * 32], Bh[64 * 32], Bl[64 * 32];
  const int z = blockIdx.z;
  const int zstart = z * 151;
  const int nsteps = (z < 3) ? 151 : 150;
  const int mt = blockIdx.x * 64, nt = blockIdx.y * 64;
  const int tid = threadIdx.x;
  const int row = tid >> 2, cg = (tid & 3) * 8;
  const int wave = tid >> 6, lane = tid & 63;
  const int wm = (wave & 1) * 32, wn = (wave >> 1) * 32;
  const int quad = lane >> 4, l16 = lane & 15;

  f32x4 acc[2][2];
#pragma unroll
  for (int i = 0; i < 2; ++i)
#pragma unroll
    for (int j = 0; j < 2; ++j) acc[i][j] = (f32x4)0.f;

  for (int s = 0; s < nsteps; ++s) {
    const int kb = (zstart + s) * 32;
    {
      const u32* ap = A2 + (size_t)(mt + row) * K + kb + cg;
      const u32* bp = B2 + (size_t)(nt + row) * K + kb + cg;
      uint4 a0 = *(const uint4*)ap, a1 = *(const uint4*)(ap + 4);
      uint4 b0 = *(const uint4*)bp, b1 = *(const uint4*)(bp + 4);
      uint4 hi, lo;
      hi = make_uint4((a0.x & 0xFFFF) | (a0.y << 16), (a0.z & 0xFFFF) | (a0.w << 16),
                      (a1.x & 0xFFFF) | (a1.y << 16), (a1.z & 0xFFFF) | (a1.w << 16));
      lo = make_uint4((a0.x >> 16) | (a0.y & 0xFFFF0000u), (a0.z >> 16) | (a0.w & 0xFFFF0000u),
                      (a1.x >> 16) | (a1.y & 0xFFFF0000u), (a1.z >> 16) | (a1.w & 0xFFFF0000u));
      *(uint4*)&Ah[row * 32 + cg] = hi;
      *(uint4*)&Al[row * 32 + cg] = lo;
      hi = make_uint4((b0.x & 0xFFFF) | (b0.y << 16), (b0.z & 0xFFFF) | (b0.w << 16),
                      (b1.x & 0xFFFF) | (b1.y << 16), (b1.z & 0xFFFF) | (b1.w << 16));
      lo = make_uint4((b0.x >> 16) | (b0.y & 0xFFFF0000u), (b0.z >> 16) | (b0.w & 0xFFFF0000u),
                      (b1.x >> 16) | (b1.y & 0xFFFF0000u), (b1.z >> 16) | (b1.w & 0xFFFF0000u));
      *(uint4*)&Bh[row * 32 + cg] = hi;
      *(uint4*)&Bl[row * 32 + cg] = lo;
    }
    __syncthreads();
    bf16x8 ah[2], al[2], bh[2], bl[2];
#pragma unroll
    for (int mf = 0; mf < 2; ++mf) {
      int r = (wm + mf * 16 + l16) * 32 + quad * 8;
      ah[mf] = *reinterpret_cast<const bf16x8*>(&Ah[r]);
      al[mf] = *reinterpret_cast<const bf16x8*>(&Al[r]);
    }
#pragma unroll
    for (int nf = 0; nf < 2; ++nf) {
      int r = (wn + nf * 16 + l16) * 32 + quad * 8;
      bh[nf] = *reinterpret_cast<const bf16x8*>(&Bh[r]);
      bl[nf] = *reinterpret_cast<const bf16x8*>(&Bl[r]);
    }
#pragma unroll
    for (int mf = 0; mf < 2; ++mf)
#pragma unroll
      for (int nf = 0; nf < 2; ++nf) {
        acc[mf][nf] = __builtin_amdgcn_mfma_f32_16x16x32_bf16(ah[mf], bh[nf], acc[mf][nf], 0, 0, 0);
        acc[mf][nf] = __builtin_amdgcn_mfma_f32_16x16x32_bf16(ah[mf], bl[nf], acc[mf][nf], 0, 0, 0);
        acc[mf][nf] = __builtin_amdgcn_mfma_f32_16x16x32_bf16(al[mf], bh[nf], acc[mf][nf], 0, 0, 0);
      }
    __syncthreads();
  }

#pragma unroll
  for (int mf = 0; mf < 2; ++mf)
#pragma unroll
    for (int nf = 0; nf < 2; ++nf)
#pragma unroll
      for (int r = 0; r < 4; ++r) {
        int rw = mt + wm + mf * 16 + quad * 4 + r;
        int cl = nt + wn + nf * 16 + l16;
        atomicAdd(&C[(size_t)rw * N + cl], acc[mf][nf][r]);
      }
}

// ---------------- fp32 GEMM NT (gx0 = xp @ Wih0^T + bih0) ----------------
#define GBM 64
#define GBN 64
#define GBK 64
#define GLD 76

__global__ __launch_bounds__(256, 2)
void gemm_nt(const float* __restrict__ A, const float* __restrict__ B,
             float* __restrict__ C, const float* __restrict__ bias,
             int M, int N, int K)
{
  __shared__ float As[GBM][GLD];
  __shared__ float Bs[GBN][GLD];
  const int mt = blockIdx.x, nt = blockIdx.y;
  const int tid = threadIdx.x;
  const int tx = tid & 15, ty = tid >> 4;

  float acc[4][4] = {{0.f}};

  for (int kb = 0; kb < K; kb += GBK) {
#pragma unroll
    for (int i = 0; i < 4; ++i) {
      int r = ty + i * 16;
      int gk = kb + tx * 4;
      *(float4*)&As[r][tx * 4] = *(const float4*)(A + (size_t)(mt * GBM + r) * K + gk);
      *(float4*)&Bs[r][tx * 4] = *(const float4*)(B + (size_t)(nt * GBN + r) * K + gk);
    }
    __syncthreads();
#pragma unroll
    for (int k4 = 0; k4 < GBK; k4 += 4) {
      float4 a[4], b[4];
#pragma unroll
      for (int i = 0; i < 4; ++i) a[i] = *(const float4*)&As[ty * 4 + i][k4];
#pragma unroll
      for (int j = 0; j < 4; ++j) b[j] = *(const float4*)&Bs[tx * 4 + j][k4];
#pragma unroll
      for (int i = 0; i < 4; ++i)
#pragma unroll
        for (int j = 0; j < 4; ++j) {
          acc[i][j] = fmaf(a[i].x, b[j].x, acc[i][j]);
          acc[i][j] = fmaf(a[i].y, b[j].y, acc[i][j]);
          acc[i][j] = fmaf(a[i].z, b[j].z, acc[i][j]);
          acc[i][j] = fmaf(a[i].w, b[j].w, acc[i][j]);
        }
    }
    __syncthreads();
  }

#pragma unroll
  for (int i = 0; i < 4; ++i) {
    int m = mt * GBM + ty * 4 + i;
#pragma unroll
    for (int j = 0; j < 4; ++j) {
      int n = nt * GBN + tx * 4 + j;
      C[(size_t)m * N + n] = acc[i][j] + bias[n];
    }
  }
}

__global__ void init_xproj(float* __restrict__ xp, const float* __restrict__ b_in) {
  int i = blockIdx.x * 256 + threadIdx.x;
  xp[i] = b_in[i & (H - 1)];
}

__global__ void out_proj(const float* __restrict__ hs1, const float* __restrict__ Wout,
                         const float* __restrict__ bout, float* __restrict__ out) {
  int idx = blockIdx.x * 256 + threadIdx.x;
  if (idx >= STEPS * OUTN) return;
  int t = idx / OUTN, o = idx - t * OUTN;
  const float* h = hs1 + t * H;
  const float* wr = Wout + o * H;
  float acc = 0.f;
#pragma unroll 4
  for (int i = 0; i < H; i += 4) {
    float4 hv = *(const float4*)(h + i);
    float4 wv = *(const float4*)(wr + i);
    acc = fmaf(hv.x, wv.x, acc);
    acc = fmaf(hv.y, wv.y, acc);
    acc = fmaf(hv.z, wv.z, acc);
    acc = fmaf(hv.w, wv.w, acc);
  }
  out[idx] = acc + bout[o];
}

// ---------------- persistent dataflow double-chain LSTM ----------------
// R4 structure + XCD CO-LOCATION + local-L2 shadow mailboxes.
// 256 WGs launched (all resident). Each reads its XCD (HW_REG_XCC_ID via
// numeric s_getreg imm 63508 = id20/off0/size32), registers in an agent table;
// after all 256 register, argmax(count) picks the winner XCD (pigeonhole: >=32
// WGs there, so 24 roles ALWAYS fill -> hang-free even if getreg returns junk).
// First 24 claimers on the winner become roles, rest exit. Roles thus share one
// XCD L2. Producers double-store: plain store to shadow lmb (dirty line in the
// SHARED L2) + agent store to mb (proven R1 path). Consumers: 6 sc0 polls on
// lmb (shared-L2 hit ~250cy when co-located) then 1 agent rescue on mb.
// Worst case on any wrong assumption == R1 exactly; best case hop ~5x cheaper.
#define NC0 24   // consumers of h0 (8 chain0 + 16 chain1)
#define NC1 16   // consumers of h1 (16 chain1)
#define RD 8     // ring depth
#define NWG 256

__global__ __launch_bounds__(512, 1)
void lstm_chains(const float* __restrict__ gx0,
                 const float* __restrict__ Whh0, const float* __restrict__ bhh0,
                 const float* __restrict__ Wih1, const float* __restrict__ Whh1,
                 const float* __restrict__ bih1, const float* __restrict__ bhh1,
                 float* __restrict__ hs1, float* __restrict__ out,
                 ull* __restrict__ mb0, ull* __restrict__ mb1,
                 int* __restrict__ flags1, int* __restrict__ claim,
                 ull* __restrict__ lmb0, ull* __restrict__ lmb1)
{
  const int tid = threadIdx.x;
  __shared__ int s_role;

  // ---- co-location claim (one-time; all 256 WGs resident => no hang) ----
  if (tid == 0) {
    u32 xid = ((u32)__builtin_amdgcn_s_getreg(63508)) & 7u;  // HW_REG_XCC_ID
    __hip_atomic_fetch_add(&claim[xid * 16], 1, __ATOMIC_SEQ_CST, __HIP_MEMORY_SCOPE_AGENT);
    __hip_atomic_fetch_add(&claim[128], 1, __ATOMIC_SEQ_CST, __HIP_MEMORY_SCOPE_AGENT);
    while (__hip_atomic_load(&claim[128], __ATOMIC_SEQ_CST, __HIP_MEMORY_SCOPE_AGENT) < NWG)
      __builtin_amdgcn_s_sleep(8);
    int best = 0, bc = -1;
    for (int i = 0; i < 8; ++i) {
      int c = __hip_atomic_load(&claim[i * 16], __ATOMIC_SEQ_CST, __HIP_MEMORY_SCOPE_AGENT);
      if (c > bc) { bc = c; best = i; }
    }
    int role = -1;
    if ((int)xid == best) {
      int s = __hip_atomic_fetch_add(&claim[144], 1, __ATOMIC_SEQ_CST, __HIP_MEMORY_SCOPE_AGENT);
      if (s < 24) role = s;
    }
    s_role = role;
  }
  __syncthreads();
  const int wg = s_role;
  if (wg < 0) return;
  const bool role0 = (wg < 8);

  __shared__ __align__(16) u32 hl_u[512];
  __shared__ __align__(16) float gbuf[256];
  __shared__ __align__(16) float gxb[256];
  __shared__ __align__(16) u32 pbuf[32];   // cell-output pair relay for fanout

  half2v wgt[8][16];
  float bias[8];
  int rg, ch;

  if (role0) {
    rg = tid >> 4; ch = tid & 15;
    int g = rg >> 3, lub = (rg & 7) * 8;
    int growb = (g << 9) + (wg << 6) + lub;
    const float* wb = Whh0 + (size_t)growb * H + ch * 32;
#pragma unroll
    for (int r = 0; r < 8; ++r) {
      const float* wr = wb + (size_t)r * H;
#pragma unroll
      for (int j4 = 0; j4 < 8; ++j4) {
        float4 f = *(const float4*)(wr + j4 * 4);
        wgt[r][2 * j4]     = half2v{(_Float16)f.x, (_Float16)f.y};
        wgt[r][2 * j4 + 1] = half2v{(_Float16)f.z, (_Float16)f.w};
      }
      bias[r] = bhh0[growb + r];
    }
  } else {
    rg = tid >> 5; ch = tid & 31;
    int g = rg >> 2, lub = (rg & 3) * 8;
    int growb = (g << 9) + ((wg - 8) << 5) + lub;
    const float* wb = (ch < 16) ? (Whh1 + (size_t)growb * H + ch * 32)
                                : (Wih1 + (size_t)growb * H + (ch - 16) * 32);
#pragma unroll
    for (int r = 0; r < 8; ++r) {
      const float* wr = wb + (size_t)r * H;
#pragma unroll
      for (int j4 = 0; j4 < 8; ++j4) {
        float4 f = *(const float4*)(wr + j4 * 4);
        wgt[r][2 * j4]     = half2v{(_Float16)f.x, (_Float16)f.y};
        wgt[r][2 * j4 + 1] = half2v{(_Float16)f.z, (_Float16)f.w};
      }
      bias[r] = bih1[growb + r] + bhh1[growb + r];
    }
  }

  float c_state = 0.f, h_last = 0.f;

  if (role0) {
    const int w = wg;
    for (int t = 0; t < STEPS; ++t) {
      if (tid >= 256) {
        int j = tid - 256;
        gxb[j] = gx0[t * 2048 + ((j >> 6) << 9) + (w << 6) + (j & 63)];
        // ring-reuse throttle: every 4th tick require chain1 past round t-4
        // (covers overwrites t..t+3). flag[w][j]: private line, 1 writer 1 poller.
        if (j < 16 && (t & 3) == 0 && t > 0) {
          int need = t - 4, f;
          const int* fp = flags1 + ((w << 4) + j) * 16;
          do {
            f = __hip_atomic_load(fp, __ATOMIC_RELAXED, __HIP_MEMORY_SCOPE_AGENT);
          } while (f < need);
        }
      } else {
        // poll private copy of h0[t-1]: slot (t-1)&7, tag t.
        const int idx = ((((w << 3) | ((t + RD - 1) & (RD - 1)))) << 8) + tid;
        ull p = poll2(lmb0 + idx, mb0 + idx, (unsigned)t);
        hl_u[tid] = (u32)p;
      }
      __syncthreads();

      float accv[8];
#pragma unroll
      for (int r = 0; r < 8; ++r) accv[r] = 0.f;
      {
        const u32* hp = hl_u + (ch << 4);
        uint4 q0 = *(const uint4*)hp;
        uint4 q1 = *(const uint4*)(hp + 4);
        uint4 q2 = *(const uint4*)(hp + 8);
        uint4 q3 = *(const uint4*)(hp + 12);
        half2v h2[16] = {bch2(q0.x), bch2(q0.y), bch2(q0.z), bch2(q0.w),
                         bch2(q1.x), bch2(q1.y), bch2(q1.z), bch2(q1.w),
                         bch2(q2.x), bch2(q2.y), bch2(q2.z), bch2(q2.w),
                         bch2(q3.x), bch2(q3.y), bch2(q3.z), bch2(q3.w)};
#pragma unroll
        for (int j = 0; j < 16; ++j)
#pragma unroll
          for (int r = 0; r < 8; ++r)
            accv[r] = dot2acc(wgt[r][j], h2[j], accv[r]);
      }
#pragma unroll
      for (int o = 1; o < 16; o <<= 1)
#pragma unroll
        for (int r = 0; r < 8; ++r)
          accv[r] += __shfl_xor(accv[r], o);
      if (ch == 0) {
        float4 ga = *(const float4*)&gxb[rg * 8];
        float4 gb = *(const float4*)&gxb[rg * 8 + 4];
        float4 o0 = make_float4(accv[0] + bias[0] + ga.x, accv[1] + bias[1] + ga.y,
                                accv[2] + bias[2] + ga.z, accv[3] + bias[3] + ga.w);
        float4 o1 = make_float4(accv[4] + bias[4] + gb.x, accv[5] + bias[5] + gb.y,
                                accv[6] + bias[6] + gb.z, accv[7] + bias[7] + gb.w);
        *(float4*)&gbuf[rg * 8] = o0;
        *(float4*)&gbuf[rg * 8 + 4] = o1;
      }
      __syncthreads();

      if (tid < 64) {
        float gi = gbuf[tid], gf = gbuf[64 + tid], gg = gbuf[128 + tid], go = gbuf[192 + tid];
        c_state = sigm(gf) * c_state + sigm(gi) * tanhf(gg);
        float hv = sigm(go) * tanhf(c_state);
        float hnb = __shfl_down(hv, 1);
        if ((tid & 1) == 0)
          pbuf[tid >> 1] = (u32)f16bits(hv) | ((u32)f16bits(hnb) << 16);
        h_last = hv;
      }
      __syncthreads();

      // wave-spread fanout: waves 4-7, 3 consumer-pairs each, local+agent stores.
      if (tid >= 256) {
        const int q = (tid >> 6) - 4;
        const int l = tid & 63, half = l >> 5, p = l & 31;
        const ull pay = ((ull)(unsigned)(t + 1) << 32) | (ull)pbuf[p];
        const int slot = t & (RD - 1);
        const int base = (w << 5) + p;
        const int cb = q + (half << 2);
        const int i0 = (((cb << 3) | slot) << 8) + base;
        const int i1 = ((((8 + cb) << 3) | slot) << 8) + base;
        const int i2 = ((((16 + cb) << 3) | slot) << 8) + base;
        st_local(lmb0 + i0, pay);
        st_local(lmb0 + i1, pay);
        st_local(lmb0 + i2, pay);
        st_pair(mb0 + i0, pay);
        st_pair(mb0 + i1, pay);
        st_pair(mb0 + i2, pay);
      }
    }
  } else {
    const int v = wg - 8;
    for (int tau = 1; tau <= STEPS; ++tau) {
      const int t = tau - 1;
      if (tid < 256) {
        // private copy of h1[t-1]: slot (t-1)&7, tag t
        const int idx = ((((v << 3) | ((t + RD - 1) & (RD - 1)))) << 8) + tid;
        ull p = poll2(lmb1 + idx, mb1 + idx, (unsigned)t);
        hl_u[tid] = (u32)p;
      } else {
        // private copy of h0[t]: slot t&7, tag t+1, consumer index 8+v.
        const int idx = (((((8 + v) << 3) | (t & (RD - 1)))) << 8) + (tid - 256);
        ull p = poll2(lmb0 + idx, mb0 + idx, (unsigned)(t + 1));
        hl_u[tid] = (u32)p;
      }
      __syncthreads();

      float accv[8];
#pragma unroll
      for (int r = 0; r < 8; ++r) accv[r] = 0.f;
      {
        const u32* hp = hl_u + (ch << 4);
        uint4 q0 = *(const uint4*)hp;
        uint4 q1 = *(const uint4*)(hp + 4);
        uint4 q2 = *(const uint4*)(hp + 8);
        uint4 q3 = *(const uint4*)(hp + 12);
        half2v h2[16] = {bch2(q0.x), bch2(q0.y), bch2(q0.z), bch2(q0.w),
                         bch2(q1.x), bch2(q1.y), bch2(q1.z), bch2(q1.w),
                         bch2(q2.x), bch2(q2.y), bch2(q2.z), bch2(q2.w),
                         bch2(q3.x), bch2(q3.y), bch2(q3.z), bch2(q3.w)};
#pragma unroll
        for (int j = 0; j < 16; ++j)
#pragma unroll
          for (int r = 0; r < 8; ++r)
            accv[r] = dot2acc(wgt[r][j], h2[j], accv[r]);
      }
#pragma unroll
      for (int o = 1; o < 32; o <<= 1)
#pragma unroll
        for (int r = 0; r < 8; ++r)
          accv[r] += __shfl_xor(accv[r], o);
      if (ch == 0) {
        float4 o0 = make_float4(accv[0] + bias[0], accv[1] + bias[1],
                                accv[2] + bias[2], accv[3] + bias[3]);
        float4 o1 = make_float4(accv[4] + bias[4], accv[5] + bias[5],
                                accv[6] + bias[6], accv[7] + bias[7]);
        *(float4*)&gbuf[rg * 8] = o0;
        *(float4*)&gbuf[rg * 8 + 4] = o1;
      }
      __syncthreads();

      if (tid < 32) {
        int u = (v << 5) + tid;
        float gi = gbuf[tid], gf = gbuf[32 + tid], gg = gbuf[64 + tid], go = gbuf[96 + tid];
        c_state = sigm(gf) * c_state + sigm(gi) * tanhf(gg);
        float hv = sigm(go) * tanhf(c_state);
        float hnb = __shfl_down(hv, 1);
        if ((tid & 1) == 0)
          pbuf[tid >> 1] = (u32)f16bits(hv) | ((u32)f16bits(hnb) << 16);
        h_last = hv;
        hs1[t * H + u] = hv;               // plain cached store; flushed at kernel end
      }
      // progress flags: every 4th tick, wave-1 threads 64..71 store tau to the
      // private flag line flag[w][v] (w = tid-64).
      if (((tau & 3) == 0) && tid >= 64 && tid < 72)
        __hip_atomic_store(flags1 + (((tid - 64) << 4) + v) * 16, tau,
                           __ATOMIC_RELAXED, __HIP_MEMORY_SCOPE_AGENT);
      __syncthreads();

      // wave-spread fanout: waves 0-3, 2 consumer-pairs each, local+agent stores.
      if (tid < 256) {
        const int q = tid >> 6;
        const int l = tid & 63, half = l >> 5, p = l & 31;
        if (p < 16) {
          const ull pay = ((ull)(unsigned)(t + 1) << 32) | (ull)pbuf[p];
          const int slot = t & (RD - 1);
          const int base = (v << 4) + p;
          const int cb = q + (half << 2);
          const int i0 = (((cb << 3) | slot) << 8) + base;
          const int i1 = ((((8 + cb) << 3) | slot) << 8) + base;
          st_local(lmb1 + i0, pay);
          st_local(lmb1 + i1, pay);
          st_pair(mb1 + i0, pay);
          st_pair(mb1 + i1, pay);
        }
      }
    }
  }

  // finals: hn at [11264,12288), cn at [12288,13312)
  if (role0) {
    if (tid < 64) {
      int u = (wg << 6) + tid;
      out[STEPS * OUTN + u] = h_last;
      out[STEPS * OUTN + 2 * H + u] = c_state;
    }
  } else {
    if (tid < 32) {
      int u = ((wg - 8) << 5) + tid;
      out[STEPS * OUTN + H + u] = h_last;
      out[STEPS * OUTN + 3 * H + u] = c_state;
    }
  }
}

// ---------------- host launch ----------------
extern "C" void kernel_launch(void* const* d_in, const int* in_sizes, int n_in,
                              void* d_out, int out_size, void* d_ws, size_t ws_size,
                              hipStream_t stream)
{
  (void)in_sizes; (void)n_in; (void)out_size; (void)ws_size;
  float* inputs = (float*)d_in[0];
  float* W_in   = (float*)d_in[1];
  const float* b_in   = (const float*)d_in[2];
  const float* Wih0   = (const float*)d_in[3];
  const float* Whh0   = (const float*)d_in[4];
  const float* bih0   = (const float*)d_in[5];
  const float* bhh0   = (const float*)d_in[6];
  const float* Wih1   = (const float*)d_in[7];
  const float* Whh1   = (const float*)d_in[8];
  const float* bih1   = (const float*)d_in[9];
  const float* bhh1   = (const float*)d_in[10];
  const float* W_out  = (const float*)d_in[11];
  const float* b_out  = (const float*)d_in[12];
  float* out = (float*)d_out;
  float* ws = (float*)d_ws;

  float* xp  = ws;                        // 1024*512
  float* gx0 = ws + 524288;               // 1024*2048
  float* hs1 = ws + 524288 + 2097152;     // 1024*512
  char* syncb = (char*)(ws + 3145728);    // 12 MB offset
  ull* mb0    = (ull*)syncb;                      // 384 KB
  ull* mb1    = (ull*)(syncb + 393216);           // 256 KB
  int* flags1 = (int*)(syncb + 655360);           // 8 KB
  int* claim  = (int*)(syncb + 663552);           // 1 KB
  ull* lmb0   = (ull*)(syncb + 664576);           // 384 KB (local shadow)
  ull* lmb1   = (ull*)(syncb + 1057792);          // 256 KB (local shadow)

  hipMemsetAsync(syncb, 0, 1319936, stream);

  {
    const int nA = STEPS * 19296;
    const int n4 = (nA + H * 19296) / 4;
    cvt_split<<<n4 / 256, 256, 0, stream>>>(inputs, W_in, nA, n4);
  }
  init_xproj<<<2048, 256, 0, stream>>>(xp, b_in);
  {
    dim3 g(16, 8, 4);
    gemm_hilo<<<g, 256, 0, stream>>>((const u32*)inputs, (const u32*)W_in, xp,
                                     1024, 512, 19296);
  }
  {
    dim3 g(16, 32, 1);
    gemm_nt<<<g, 256, 0, stream>>>(xp, Wih0, gx0, bih0, 1024, 2048, 512);
  }
  lstm_chains<<<NWG, 512, 0, stream>>>(gx0, Whh0, bhh0, Wih1, Whh1, bih1, bhh1,
                                       hs1, out, mb0, mb1, flags1, claim, lmb0, lmb1);
  out_proj<<<44, 256, 0, stream>>>(hs1, W_out, b_out, out);
}

// Round 6
// 3098.172 us; speedup vs baseline: 1.1394x; 1.1394x over previous
//
#include <hip/hip_runtime.h>
#include <math.h>

typedef unsigned long long ull;
typedef unsigned int u32;
typedef unsigned short u16;
typedef _Float16 half2v __attribute__((ext_vector_type(2)));
typedef __bf16 bf16x8 __attribute__((ext_vector_type(8)));
typedef float f32x4 __attribute__((ext_vector_type(4)));

#define H 512
#define STEPS 1024
#define OUTN 11

__device__ __forceinline__ float sigm(float x) { return 1.f / (1.f + __expf(-x)); }
__device__ __forceinline__ ull ld_pair(const ull* p) {
  return __hip_atomic_load((ull*)p, __ATOMIC_RELAXED, __HIP_MEMORY_SCOPE_AGENT);
}
__device__ __forceinline__ void st_pair(ull* p, ull v) {
  __hip_atomic_store(p, v, __ATOMIC_RELAXED, __HIP_MEMORY_SCOPE_AGENT);
}
__device__ __forceinline__ float dot2acc(half2v a, half2v b, float c) {
#if __has_builtin(__builtin_amdgcn_fdot2)
  return __builtin_amdgcn_fdot2(a, b, c, false);
#else
  return c + (float)a.x * (float)b.x + (float)a.y * (float)b.y;
#endif
}
__device__ __forceinline__ u16 f16bits(float x) {
  return __builtin_bit_cast(u16, (_Float16)x);
}
__device__ __forceinline__ half2v bch2(u32 u) { return __builtin_bit_cast(half2v, u); }

// ---------- in-place fp32 -> {bf16 hi, bf16 lo} repack (same 4B/elem) ----------
__device__ __forceinline__ u32 split_bf16(float x) {
  u32 u = __float_as_uint(x);
  u32 rh = (u + 0x7FFFu + ((u >> 16) & 1u)) & 0xFFFF0000u;
  float hf = __uint_as_float(rh);
  float lo = x - hf;
  u32 ul = __float_as_uint(lo);
  u32 rl = (ul + 0x7FFFu + ((ul >> 16) & 1u)) & 0xFFFF0000u;
  return (rh >> 16) | rl;
}

__global__ void cvt_split(float* __restrict__ A, float* __restrict__ B, int nA, int n4) {
  int idx = blockIdx.x * 256 + threadIdx.x;
  if (idx >= n4) return;
  int base = idx * 4;
  float* p = (base < nA) ? (A + base) : (B + (base - nA));
  float4 v = *(float4*)p;
  u32 r0 = split_bf16(v.x), r1 = split_bf16(v.y), r2 = split_bf16(v.z), r3 = split_bf16(v.w);
  uint4 o = make_uint4(r0, r1, r2, r3);
  *(uint4*)p = o;
}

// ---------- MFMA hi/lo bf16 GEMM: xp[M,N] += A[M,K] * B[N,K]^T (split-K atomic) ----------
__global__ __launch_bounds__(256, 2)
void gemm_hilo(const u32* __restrict__ A2, const u32* __restrict__ B2,
               float* __restrict__ C, int M, int N, int K)
{
  __shared__ __align__(16) u16 Ah[64 * 32], Al[64 * 32], Bh[64 * 32], Bl[64 * 32];
  const int z = blockIdx.z;
  const int zstart = z * 151;
  const int nsteps = (z < 3) ? 151 : 150;
  const int mt = blockIdx.x * 64, nt = blockIdx.y * 64;
  const int tid = threadIdx.x;
  const int row = tid >> 2, cg = (tid & 3) * 8;
  const int wave = tid >> 6, lane = tid & 63;
  const int wm = (wave & 1) * 32, wn = (wave >> 1) * 32;
  const int quad = lane >> 4, l16 = lane & 15;

  f32x4 acc[2][2];
#pragma unroll
  for (int i = 0; i < 2; ++i)
#pragma unroll
    for (int j = 0; j < 2; ++j) acc[i][j] = (f32x4)0.f;

  for (int s = 0; s < nsteps; ++s) {
    const int kb = (zstart + s) * 32;
    {
      const u32* ap = A2 + (size_t)(mt + row) * K + kb + cg;
      const u32* bp = B2 + (size_t)(nt + row) * K + kb + cg;
      uint4 a0 = *(const uint4*)ap, a1 = *(const uint4*)(ap + 4);
      uint4 b0 = *(const uint4*)bp, b1 = *(const uint4*)(bp + 4);
      uint4 hi, lo;
      hi = make_uint4((a0.x & 0xFFFF) | (a0.y << 16), (a0.z & 0xFFFF) | (a0.w << 16),
                      (a1.x & 0xFFFF) | (a1.y << 16), (a1.z & 0xFFFF) | (a1.w << 16));
      lo = make_uint4((a0.x >> 16) | (a0.y & 0xFFFF0000u), (a0.z >> 16) | (a0.w & 0xFFFF0000u),
                      (a1.x >> 16) | (a1.y & 0xFFFF0000u), (a1.z >> 16) | (a1.w & 0xFFFF0000u));
      *(uint4*)&Ah[row * 32 + cg] = hi;
      *(uint4*)&Al[row * 32 + cg] = lo;
      hi = make_uint4((b0.x & 0xFFFF) | (b0.y << 16), (b0.z & 0xFFFF) | (b0.w << 16),
                      (b1.x & 0xFFFF) | (b1.y << 16), (b1.z & 0xFFFF) | (b1.w << 16));
      lo = make_uint4((b0.x >> 16) | (b0.y & 0xFFFF0000u), (b0.z >> 16) | (b0.w & 0xFFFF0000u),
                      (b1.x >> 16) | (b1.y & 0xFFFF0000u), (b1.z >> 16) | (b1.w & 0xFFFF0000u));
      *(uint4*)&Bh[row * 32 + cg] = hi;
      *(uint4*)&Bl[row * 32 + cg] = lo;
    }
    __syncthreads();
    bf16x8 ah[2], al[2], bh[2], bl[2];
#pragma unroll
    for (int mf = 0; mf < 2; ++mf) {
      int r = (wm + mf * 16 + l16) * 32 + quad * 8;
      ah[mf] = *reinterpret_cast<const bf16x8*>(&Ah[r]);
      al[mf] = *reinterpret_cast<const bf16x8*>(&Al[r]);
    }
#pragma unroll
    for (int nf = 0; nf < 2; ++nf) {
      int r = (wn + nf * 16 + l16) * 32 + quad * 8;
      bh[nf] = *reinterpret_cast<const bf16x8*>(&Bh[r]);
      bl[nf] = *reinterpret_cast<const bf16x8*>(&Bl[r]);
    }
#pragma unroll
    for (int mf = 0; mf < 2; ++mf)
#pragma unroll
      for (int nf = 0; nf < 2; ++nf) {
        acc[mf][nf] = __builtin_amdgcn_mfma_f32_16x16x32_bf16(ah[mf], bh[nf], acc[mf][nf], 0, 0, 0);
        acc[mf][nf] = __builtin_amdgcn_mfma_f32_16x16x32_bf16(ah[mf], bl[nf], acc[mf][nf], 0, 0, 0);
        acc[mf][nf] = __builtin_amdgcn_mfma_f32_16x16x32_bf16(al[mf], bh[nf], acc[mf][nf], 0, 0, 0);
      }
    __syncthreads();
  }

#pragma unroll
  for (int mf = 0; mf < 2; ++mf)
#pragma unroll
    for (int nf = 0; nf < 2; ++nf)
#pragma unroll
      for (int r = 0; r < 4; ++r) {
        int rw = mt + wm + mf * 16 + quad * 4 + r;
        int cl = nt + wn + nf * 16 + l16;
        atomicAdd(&C[(size_t)rw * N + cl], acc[mf][nf][r]);
      }
}

// ---------------- fp32 GEMM NT (gx0 = xp @ Wih0^T + bih0) ----------------
#define GBM 64
#define GBN 64
#define GBK 64
#define GLD 76

__global__ __launch_bounds__(256, 2)
void gemm_nt(const float* __restrict__ A, const float* __restrict__ B,
             float* __restrict__ C, const float* __restrict__ bias,
             int M, int N, int K)
{
  __shared__ float As[GBM][GLD];
  __shared__ float Bs[GBN][GLD];
  const int mt = blockIdx.x, nt = blockIdx.y;
  const int tid = threadIdx.x;
  const int tx = tid & 15, ty = tid >> 4;

  float acc[4][4] = {{0.f}};

  for (int kb = 0; kb < K; kb += GBK) {
#pragma unroll
    for (int i = 0; i < 4; ++i) {
      int r = ty + i * 16;
      int gk = kb + tx * 4;
      *(float4*)&As[r][tx * 4] = *(const float4*)(A + (size_t)(mt * GBM + r) * K + gk);
      *(float4*)&Bs[r][tx * 4] = *(const float4*)(B + (size_t)(nt * GBN + r) * K + gk);
    }
    __syncthreads();
#pragma unroll
    for (int k4 = 0; k4 < GBK; k4 += 4) {
      float4 a[4], b[4];
#pragma unroll
      for (int i = 0; i < 4; ++i) a[i] = *(const float4*)&As[ty * 4 + i][k4];
#pragma unroll
      for (int j = 0; j < 4; ++j) b[j] = *(const float4*)&Bs[tx * 4 + j][k4];
#pragma unroll
      for (int i = 0; i < 4; ++i)
#pragma unroll
        for (int j = 0; j < 4; ++j) {
          acc[i][j] = fmaf(a[i].x, b[j].x, acc[i][j]);
          acc[i][j] = fmaf(a[i].y, b[j].y, acc[i][j]);
          acc[i][j] = fmaf(a[i].z, b[j].z, acc[i][j]);
          acc[i][j] = fmaf(a[i].w, b[j].w, acc[i][j]);
        }
    }
    __syncthreads();
  }

#pragma unroll
  for (int i = 0; i < 4; ++i) {
    int m = mt * GBM + ty * 4 + i;
#pragma unroll
    for (int j = 0; j < 4; ++j) {
      int n = nt * GBN + tx * 4 + j;
      C[(size_t)m * N + n] = acc[i][j] + bias[n];
    }
  }
}

__global__ void init_xproj(float* __restrict__ xp, const float* __restrict__ b_in) {
  int i = blockIdx.x * 256 + threadIdx.x;
  xp[i] = b_in[i & (H - 1)];
}

__global__ void out_proj(const float* __restrict__ hs1, const float* __restrict__ Wout,
                         const float* __restrict__ bout, float* __restrict__ out) {
  int idx = blockIdx.x * 256 + threadIdx.x;
  if (idx >= STEPS * OUTN) return;
  int t = idx / OUTN, o = idx - t * OUTN;
  const float* h = hs1 + t * H;
  const float* wr = Wout + o * H;
  float acc = 0.f;
#pragma unroll 4
  for (int i = 0; i < H; i += 4) {
    float4 hv = *(const float4*)(h + i);
    float4 wv = *(const float4*)(wr + i);
    acc = fmaf(hv.x, wv.x, acc);
    acc = fmaf(hv.y, wv.y, acc);
    acc = fmaf(hv.z, wv.z, acc);
    acc = fmaf(hv.w, wv.w, acc);
  }
  out[idx] = acc + bout[o];
}

// ---------------- persistent dataflow double-chain LSTM, private mailboxes ----------------
// EXACT R4 structure (proven 2690us) + CLOCK-KEEPER FILLERS (blocks 24..255).
// Theory: the ~2.2us publish->detect hop is the MALL round trip stretched ~4x by
// DPM downclocking (24 WGs at 2% VALU = near-idle chip -> clock floor). R3/R4/R5
// proved store-drain, poll cadence, and cache-path restructuring all move nothing;
// the remaining multiplicative factor is clock. Fillers spin register-only FMA on
// the other 232 block slots to hold the DPM at high clock; they read one shared
// done-flag line (read-only -> no ownership traffic) and exit when role0-WG0
// finishes, with an iteration cap as an absolute termination bound. No interaction
// with mailbox lines; worst case is R4 + minor co-residency contention.
#define NC0 24   // consumers of h0 (8 chain0 + 16 chain1)
#define NC1 16   // consumers of h1 (16 chain1)
#define RD 8     // ring depth
#define NROLE 24
#define NWG 256

__global__ __launch_bounds__(512, 1)
void lstm_chains(const float* __restrict__ gx0,
                 const float* __restrict__ Whh0, const float* __restrict__ bhh0,
                 const float* __restrict__ Wih1, const float* __restrict__ Whh1,
                 const float* __restrict__ bih1, const float* __restrict__ bhh1,
                 float* __restrict__ hs1, float* __restrict__ out,
                 ull* __restrict__ mb0, ull* __restrict__ mb1,
                 int* __restrict__ flags1, int* __restrict__ done)
{
  const int wg = blockIdx.x;
  const int tid = threadIdx.x;

  // ---- clock-keeper fillers: register-only FMA spin, exit on done flag ----
  if (wg >= NROLE) {
    float b = 1.0000001f, c = 1e-7f;
    float a0 = (float)tid, a1 = a0 + 1.f, a2 = a0 + 2.f, a3 = a0 + 3.f;
    for (int it = 0; it < 8000; ++it) {
#pragma unroll 32
      for (int i = 0; i < 512; ++i) {
        a0 = fmaf(a0, b, c); a1 = fmaf(a1, b, c);
        a2 = fmaf(a2, b, c); a3 = fmaf(a3, b, c);
      }
      asm volatile("" :: "v"(a0), "v"(a1), "v"(a2), "v"(a3));
      if (__hip_atomic_load(done, __ATOMIC_RELAXED, __HIP_MEMORY_SCOPE_AGENT) != 0)
        break;
    }
    return;
  }

  const bool role0 = (wg < 8);

  __shared__ __align__(16) u32 hl_u[512];
  __shared__ __align__(16) float gbuf[256];
  __shared__ __align__(16) float gxb[256];
  __shared__ __align__(16) u32 pbuf[32];   // cell-output pair relay for fanout

  half2v wgt[8][16];
  float bias[8];
  int rg, ch;

  if (role0) {
    rg = tid >> 4; ch = tid & 15;
    int g = rg >> 3, lub = (rg & 7) * 8;
    int growb = (g << 9) + (wg << 6) + lub;
    const float* wb = Whh0 + (size_t)growb * H + ch * 32;
#pragma unroll
    for (int r = 0; r < 8; ++r) {
      const float* wr = wb + (size_t)r * H;
#pragma unroll
      for (int j4 = 0; j4 < 8; ++j4) {
        float4 f = *(const float4*)(wr + j4 * 4);
        wgt[r][2 * j4]     = half2v{(_Float16)f.x, (_Float16)f.y};
        wgt[r][2 * j4 + 1] = half2v{(_Float16)f.z, (_Float16)f.w};
      }
      bias[r] = bhh0[growb + r];
    }
  } else {
    rg = tid >> 5; ch = tid & 31;
    int g = rg >> 2, lub = (rg & 3) * 8;
    int growb = (g << 9) + ((wg - 8) << 5) + lub;
    const float* wb = (ch < 16) ? (Whh1 + (size_t)growb * H + ch * 32)
                                : (Wih1 + (size_t)growb * H + (ch - 16) * 32);
#pragma unroll
    for (int r = 0; r < 8; ++r) {
      const float* wr = wb + (size_t)r * H;
#pragma unroll
      for (int j4 = 0; j4 < 8; ++j4) {
        float4 f = *(const float4*)(wr + j4 * 4);
        wgt[r][2 * j4]     = half2v{(_Float16)f.x, (_Float16)f.y};
        wgt[r][2 * j4 + 1] = half2v{(_Float16)f.z, (_Float16)f.w};
      }
      bias[r] = bih1[growb + r] + bhh1[growb + r];
    }
  }

  float c_state = 0.f, h_last = 0.f;

  if (role0) {
    const int w = wg;
    for (int t = 0; t < STEPS; ++t) {
      if (tid >= 256) {
        int j = tid - 256;
        gxb[j] = gx0[t * 2048 + ((j >> 6) << 9) + (w << 6) + (j & 63)];
        // ring-reuse throttle: every 4th tick require chain1 past round t-4
        // (covers overwrites t..t+3). flag[w][j]: private line, 1 writer 1 poller.
        if (j < 16 && (t & 3) == 0 && t > 0) {
          int need = t - 4, f;
          const int* fp = flags1 + ((w << 4) + j) * 16;
          do {
            f = __hip_atomic_load(fp, __ATOMIC_RELAXED, __HIP_MEMORY_SCOPE_AGENT);
          } while (f < need);
        }
      } else {
        // poll private copy of h0[t-1]: slot (t-1)&7, tag t.
        const ull* src = mb0 + ((((w << 3) | ((t + RD - 1) & (RD - 1)))) << 8) + tid;
        ull p;
        do { p = ld_pair(src); } while ((unsigned)(p >> 32) != (unsigned)t);
        hl_u[tid] = (u32)p;
      }
      __syncthreads();

      float accv[8];
#pragma unroll
      for (int r = 0; r < 8; ++r) accv[r] = 0.f;
      {
        const u32* hp = hl_u + (ch << 4);
        uint4 q0 = *(const uint4*)hp;
        uint4 q1 = *(const uint4*)(hp + 4);
        uint4 q2 = *(const uint4*)(hp + 8);
        uint4 q3 = *(const uint4*)(hp + 12);
        half2v h2[16] = {bch2(q0.x), bch2(q0.y), bch2(q0.z), bch2(q0.w),
                         bch2(q1.x), bch2(q1.y), bch2(q1.z), bch2(q1.w),
                         bch2(q2.x), bch2(q2.y), bch2(q2.z), bch2(q2.w),
                         bch2(q3.x), bch2(q3.y), bch2(q3.z), bch2(q3.w)};
#pragma unroll
        for (int j = 0; j < 16; ++j)
#pragma unroll
          for (int r = 0; r < 8; ++r)
            accv[r] = dot2acc(wgt[r][j], h2[j], accv[r]);
      }
#pragma unroll
      for (int o = 1; o < 16; o <<= 1)
#pragma unroll
        for (int r = 0; r < 8; ++r)
          accv[r] += __shfl_xor(accv[r], o);
      if (ch == 0) {
        float4 ga = *(const float4*)&gxb[rg * 8];
        float4 gb = *(const float4*)&gxb[rg * 8 + 4];
        float4 o0 = make_float4(accv[0] + bias[0] + ga.x, accv[1] + bias[1] + ga.y,
                                accv[2] + bias[2] + ga.z, accv[3] + bias[3] + ga.w);
        float4 o1 = make_float4(accv[4] + bias[4] + gb.x, accv[5] + bias[5] + gb.y,
                                accv[6] + bias[6] + gb.z, accv[7] + bias[7] + gb.w);
        *(float4*)&gbuf[rg * 8] = o0;
        *(float4*)&gbuf[rg * 8 + 4] = o1;
      }
      __syncthreads();

      if (tid < 64) {
        float gi = gbuf[tid], gf = gbuf[64 + tid], gg = gbuf[128 + tid], go = gbuf[192 + tid];
        c_state = sigm(gf) * c_state + sigm(gi) * tanhf(gg);
        float hv = sigm(go) * tanhf(c_state);
        float hnb = __shfl_down(hv, 1);
        if ((tid & 1) == 0)
          pbuf[tid >> 1] = (u32)f16bits(hv) | ((u32)f16bits(hnb) << 16);
        h_last = hv;
      }
      __syncthreads();

      // wave-spread fanout: waves 4-7, 3 two-copy store instructions each.
      if (tid >= 256) {
        const int q = (tid >> 6) - 4;
        const int l = tid & 63, half = l >> 5, p = l & 31;
        const ull pay = ((ull)(unsigned)(t + 1) << 32) | (ull)pbuf[p];
        const int slot = t & (RD - 1);
        const int base = (w << 5) + p;
        const int cb = q + (half << 2);
        st_pair(mb0 + (((cb << 3) | slot) << 8) + base, pay);
        st_pair(mb0 + ((((8 + cb) << 3) | slot) << 8) + base, pay);
        st_pair(mb0 + ((((16 + cb) << 3) | slot) << 8) + base, pay);
      }
    }
  } else {
    const int v = wg - 8;
    for (int tau = 1; tau <= STEPS; ++tau) {
      const int t = tau - 1;
      if (tid < 256) {
        // private copy of h1[t-1]: slot (t-1)&7, tag t
        const ull* q1 = mb1 + ((((v << 3) | ((t + RD - 1) & (RD - 1)))) << 8) + tid;
        ull p;
        do { p = ld_pair(q1); } while ((unsigned)(p >> 32) != (unsigned)t);
        hl_u[tid] = (u32)p;
      } else {
        // private copy of h0[t]: slot t&7, tag t+1, consumer index 8+v.
        const ull* q0 = mb0 + (((((8 + v) << 3) | (t & (RD - 1)))) << 8) + (tid - 256);
        ull p;
        do { p = ld_pair(q0); } while ((unsigned)(p >> 32) != (unsigned)(t + 1));
        hl_u[tid] = (u32)p;
      }
      __syncthreads();

      float accv[8];
#pragma unroll
      for (int r = 0; r < 8; ++r) accv[r] = 0.f;
      {
        const u32* hp = hl_u + (ch << 4);
        uint4 q0 = *(const uint4*)hp;
        uint4 q1 = *(const uint4*)(hp + 4);
        uint4 q2 = *(const uint4*)(hp + 8);
        uint4 q3 = *(const uint4*)(hp + 12);
        half2v h2[16] = {bch2(q0.x), bch2(q0.y), bch2(q0.z), bch2(q0.w),
                         bch2(q1.x), bch2(q1.y), bch2(q1.z), bch2(q1.w),
                         bch2(q2.x), bch2(q2.y), bch2(q2.z), bch2(q2.w),
                         bch2(q3.x), bch2(q3.y), bch2(q3.z), bch2(q3.w)};
#pragma unroll
        for (int j = 0; j < 16; ++j)
#pragma unroll
          for (int r = 0; r < 8; ++r)
            accv[r] = dot2acc(wgt[r][j], h2[j], accv[r]);
      }
#pragma unroll
      for (int o = 1; o < 32; o <<= 1)
#pragma unroll
        for (int r = 0; r < 8; ++r)
          accv[r] += __shfl_xor(accv[r], o);
      if (ch == 0) {
        float4 o0 = make_float4(accv[0] + bias[0], accv[1] + bias[1],
                                accv[2] + bias[2], accv[3] + bias[3]);
        float4 o1 = make_float4(accv[4] + bias[4], accv[5] + bias[5],
                                accv[6] + bias[6], accv[7] + bias[7]);
        *(float4*)&gbuf[rg * 8] = o0;
        *(float4*)&gbuf[rg * 8 + 4] = o1;
      }
      __syncthreads();

      if (tid < 32) {
        int u = (v << 5) + tid;
        float gi = gbuf[tid], gf = gbuf[32 + tid], gg = gbuf[64 + tid], go = gbuf[96 + tid];
        c_state = sigm(gf) * c_state + sigm(gi) * tanhf(gg);
        float hv = sigm(go) * tanhf(c_state);
        float hnb = __shfl_down(hv, 1);
        if ((tid & 1) == 0)
          pbuf[tid >> 1] = (u32)f16bits(hv) | ((u32)f16bits(hnb) << 16);
        h_last = hv;
        hs1[t * H + u] = hv;               // plain cached store; flushed at kernel end
      }
      // progress flags: every 4th tick, wave-1 threads 64..71 store tau to the
      // private flag line flag[w][v] (w = tid-64).
      if (((tau & 3) == 0) && tid >= 64 && tid < 72)
        __hip_atomic_store(flags1 + (((tid - 64) << 4) + v) * 16, tau,
                           __ATOMIC_RELAXED, __HIP_MEMORY_SCOPE_AGENT);
      __syncthreads();

      // wave-spread fanout: waves 0-3, 2 two-copy store instructions each.
      if (tid < 256) {
        const int q = tid >> 6;
        const int l = tid & 63, half = l >> 5, p = l & 31;
        if (p < 16) {
          const ull pay = ((ull)(unsigned)(t + 1) << 32) | (ull)pbuf[p];
          const int slot = t & (RD - 1);
          const int base = (v << 4) + p;
          const int cb = q + (half << 2);
          st_pair(mb1 + (((cb << 3) | slot) << 8) + base, pay);
          st_pair(mb1 + ((((8 + cb) << 3) | slot) << 8) + base, pay);
        }
      }
    }
  }

  // release the clock-keepers as soon as the first chain finishes
  if (wg == 0 && tid == 0)
    __hip_atomic_store(done, 1, __ATOMIC_RELAXED, __HIP_MEMORY_SCOPE_AGENT);

  // finals: hn at [11264,12288), cn at [12288,13312)
  if (role0) {
    if (tid < 64) {
      int u = (wg << 6) + tid;
      out[STEPS * OUTN + u] = h_last;
      out[STEPS * OUTN + 2 * H + u] = c_state;
    }
  } else {
    if (tid < 32) {
      int u = ((wg - 8) << 5) + tid;
      out[STEPS * OUTN + H + u] = h_last;
      out[STEPS * OUTN + 3 * H + u] = c_state;
    }
  }
}

// ---------------- host launch ----------------
extern "C" void kernel_launch(void* const* d_in, const int* in_sizes, int n_in,
                              void* d_out, int out_size, void* d_ws, size_t ws_size,
                              hipStream_t stream)
{
  (void)in_sizes; (void)n_in; (void)out_size; (void)ws_size;
  float* inputs = (float*)d_in[0];
  float* W_in   = (float*)d_in[1];
  const float* b_in   = (const float*)d_in[2];
  const float* Wih0   = (const float*)d_in[3];
  const float* Whh0   = (const float*)d_in[4];
  const float* bih0   = (const float*)d_in[5];
  const float* bhh0   = (const float*)d_in[6];
  const float* Wih1   = (const float*)d_in[7];
  const float* Whh1   = (const float*)d_in[8];
  const float* bih1   = (const float*)d_in[9];
  const float* bhh1   = (const float*)d_in[10];
  const float* W_out  = (const float*)d_in[11];
  const float* b_out  = (const float*)d_in[12];
  float* out = (float*)d_out;
  float* ws = (float*)d_ws;

  float* xp  = ws;                        // 1024*512
  float* gx0 = ws + 524288;               // 1024*2048
  float* hs1 = ws + 524288 + 2097152;     // 1024*512
  char* syncb = (char*)(ws + 3145728);    // 12 MB offset
  ull* mb0    = (ull*)syncb;                      // 24*8*256*8 = 384 KB
  ull* mb1    = (ull*)(syncb + 393216);           // 16*8*256*8 = 256 KB
  int* flags1 = (int*)(syncb + 655360);           // 8 KB
  int* done   = (int*)(syncb + 663552);           // 64 B

  hipMemsetAsync(syncb, 0, 663616, stream);

  {
    const int nA = STEPS * 19296;
    const int n4 = (nA + H * 19296) / 4;
    cvt_split<<<n4 / 256, 256, 0, stream>>>(inputs, W_in, nA, n4);
  }
  init_xproj<<<2048, 256, 0, stream>>>(xp, b_in);
  {
    dim3 g(16, 8, 4);
    gemm_hilo<<<g, 256, 0, stream>>>((const u32*)inputs, (const u32*)W_in, xp,
                                     1024, 512, 19296);
  }
  {
    dim3 g(16, 32, 1);
    gemm_nt<<<g, 256, 0, stream>>>(xp, Wih0, gx0, bih0, 1024, 2048, 512);
  }
  lstm_chains<<<NWG, 512, 0, stream>>>(gx0, Whh0, bhh0, Wih1, Whh1, bih1, bhh1,
                                       hs1, out, mb0, mb1, flags1, done);
  out_proj<<<44, 256, 0, stream>>>(hs1, W_out, b_out, out);
}